// Round 8
// baseline (199.024 us; speedup 1.0000x reference)
//
#include <hip/hip_runtime.h>
#include <math.h>

// Problem constants
// B=2, H=128, W=256, MD=34, LD=32, NH=4, HD=8, SH=64, K=25, P=7, R=3,
// FF1=512, FF2=256

typedef __attribute__((ext_vector_type(8))) short bfrag;    // 8 bf16 = 4 VGPR
typedef __attribute__((ext_vector_type(4))) float ffrag;    // 4 f32 acc
typedef __attribute__((ext_vector_type(4))) short short4v;  // 8B

union bfi4 { int4 i; bfrag b; };

// Fast tanh-form GELU (~7 VALU ops, |err| vs erf-GELU ~3e-3)
__device__ __forceinline__ float gelu_f(float v) {
  const float z = v * (2.3022077484f + 0.1029451564f * v * v);  // log2e folded
  const float e = __builtin_amdgcn_exp2f(-z);
  return v * __builtin_amdgcn_rcpf(1.0f + e);
}

// exact RNE (cold paths: weight prep)
__device__ __forceinline__ short f2bf(float f) {
  union { float f; unsigned u; } v; v.f = f;
  unsigned r = (v.u + 0x7fffu + ((v.u >> 16) & 1u)) >> 16;
  return (short)r;
}

// round-half-up (2 VALU ops)
__device__ __forceinline__ short f2bf_fast(float f) {
  union { float f; unsigned u; } v; v.f = f;
  return (short)((v.u + 0x8000u) >> 16);
}

__device__ __forceinline__ float bf2f(short s) {
  union { float f; unsigned u; } v;
  v.u = ((unsigned)(unsigned short)s) << 16;
  return v.f;
}

// pack two f32 -> bf16 pair in one dword: (bf(b)<<16)|bf(a); 3 VALU ops
__device__ __forceinline__ int pkbf(float a, float b) {
  union { float f; unsigned u; } va, vb; va.f = a; vb.f = b;
  return (int)__builtin_amdgcn_perm(vb.u + 0x8000u, va.u + 0x8000u, 0x07060302u);
}

// DPP cross-lane add; butterfly reduction over 16 lanes (all lanes get sum).
template <int CTRL>
__device__ __forceinline__ float dpp_add(float v) {
  union { float f; int i; } s, t;
  s.f = v;
  t.i = __builtin_amdgcn_update_dpp(0, s.i, CTRL, 0xf, 0xf, true);
  return v + t.f;
}
__device__ __forceinline__ float reduce16(float v) {
  v = dpp_add<0xB1>(v);    // quad_perm [1,0,3,2]  = xor1
  v = dpp_add<0x4E>(v);    // quad_perm [2,3,0,1]  = xor2
  v = dpp_add<0x141>(v);   // row_half_mirror      ~ xor4 after fold
  v = dpp_add<0x140>(v);   // row_mirror           ~ xor8 after fold
  return v;
}

// staged bf16 short4 store helper
__device__ __forceinline__ void st4bf(short* p, float4 v) {
  short4v s;
  s[0] = f2bf(v.x); s[1] = f2bf(v.y); s[2] = f2bf(v.z); s[3] = f2bf(v.w);
  *(short4v*)p = s;
}

// ---------------------------------------------------------------------------
// K01: all weight prep. Every fragment swizzle now goes through an
// LDS-staged transpose: global reads COALESCED (n-fast float4), fragment
// emit reads from LDS (~2-way aliased, free), writes coalesced.
// bid 0..127 : conv weights wcb[h] (two j-phase sets); dw staged in LDS.
// bid 128..143: fw2 transpose (one kt tile each).
// bid 144    : fw1 transpose.   bid 145: fw3 transpose.
// bid 146    : hw1 transpose.   bid 147: hb1e (db fold).
// ---------------------------------------------------------------------------
__global__ __launch_bounds__(256) void k01_prep(
    const float* __restrict__ psi, const float* __restrict__ dw,
    const float* __restrict__ db,
    const float* __restrict__ fw1, const float* __restrict__ fw2,
    const float* __restrict__ fw3, const float* __restrict__ hw1,
    const float* __restrict__ hb1,
    short* __restrict__ wcb, short* __restrict__ fw1s,
    short* __restrict__ fw2s, short* __restrict__ fw3s,
    short* __restrict__ hw1b, float* __restrict__ hb1e) {
  __shared__ __align__(16) char sm[33280];
  const int bid = blockIdx.x;
  const int tid = threadIdx.x;

  if (bid < 128) {            // ---- wcb: conv weight fragments per latitude
    float* psiL = (float*)sm;            // 1225 f
    float* dwL  = (float*)(sm + 4928);   // 1600 f
    const int h = bid;
    for (int e = tid; e < 1225; e += 256)
      psiL[e] = psi[(e / 49) * (128 * 49) + h * 49 + (e % 49)];
    for (int e = tid; e < 1600; e += 256) dwL[e] = dw[e];
    __syncthreads();
    short* outp = wcb + h * 8192;
    for (int idx = tid; idx < 8192; idx += 256) {
      const int jj = idx & 7, lane = (idx >> 3) & 63;
      const int nt = (idx >> 9) & 3, kt = (idx >> 11) & 1, par = idx >> 12;
      const int k = kt * 32 + (lane >> 4) * 8 + jj;
      const int f = nt * 16 + (lane & 15);
      const int r = k >> 3, dlt = k & 7;
      const int j = par ? (dlt - 1) : dlt;
      float acc = 0.f;
      if (r < 7 && j >= 0 && j < 7) {
        const int p = r * 7 + j;
#pragma unroll
        for (int kk = 0; kk < 25; ++kk)
          acc += dwL[f * 25 + kk] * psiL[kk * 49 + p];
      }
      outp[idx] = f2bf(acc);
    }
    return;
  }

  if (bid < 144) {            // ---- fw2 kt-tile transpose: K rows 32, N 256
    short* S = (short*)sm;               // [32][260]
    const int kt = bid - 128;
    const float* src = fw2 + kt * 8192;
    for (int q = tid; q < 2048; q += 256) {
      const int lin = q * 4;
      const int kk = lin >> 8, nn = lin & 255;
      st4bf(S + kk * 260 + nn, *(const float4*)(src + lin));
    }
    __syncthreads();
    short* dst = fw2s + kt * 8192;
    for (int q = tid; q < 8192; q += 256) {
      const int jj = q & 7, lane = (q >> 3) & 63, nt = q >> 9;
      const int kk = (lane >> 4) * 8 + jj, nn = nt * 16 + (lane & 15);
      dst[q] = S[kk * 260 + nn];
    }
    return;
  }

  if (bid == 144) {           // ---- fw1 transpose: K 32, N 512
    short* S = (short*)sm;               // [32][516]
    for (int q = tid; q < 4096; q += 256) {
      const int lin = q * 4;
      const int kk = lin >> 9, nn = lin & 511;
      st4bf(S + kk * 516 + nn, *(const float4*)(fw1 + lin));
    }
    __syncthreads();
    for (int q = tid; q < 16384; q += 256) {
      const int jj = q & 7, lane = (q >> 3) & 63, nt = q >> 9;
      const int kk = (lane >> 4) * 8 + jj, nn = nt * 16 + (lane & 15);
      fw1s[q] = S[kk * 516 + nn];
    }
    return;
  }

  if (bid == 145) {           // ---- fw3 transpose: K 256, N 32
    short* S = (short*)sm;               // [256][36]
    for (int q = tid; q < 2048; q += 256) {
      const int lin = q * 4;
      const int kk = lin >> 5, nn = lin & 31;
      st4bf(S + kk * 36 + nn, *(const float4*)(fw3 + lin));
    }
    __syncthreads();
    for (int q = tid; q < 8192; q += 256) {
      const int jj = q & 7, lane = (q >> 3) & 63;
      const int nt = (q >> 9) & 1, kt = q >> 10;
      const int kk = kt * 32 + (lane >> 4) * 8 + jj, nn = nt * 16 + (lane & 15);
      fw3s[q] = S[kk * 36 + nn];
    }
    return;
  }

  if (bid == 146) {           // ---- hw1 transpose (slot-K): rows (n,s), N 32
    short* S = (short*)sm;               // [256][36]
    for (int q = tid; q < 2048; q += 256) {
      const int lin = q * 4;
      const int row = lin >> 5, nn = lin & 31;
      st4bf(S + row * 36 + nn, *(const float4*)(hw1 + lin));
    }
    __syncthreads();
    for (int q = tid; q < 8192; q += 256) {
      const int jj = q & 7, lane = (q >> 3) & 63;
      const int fr = (q >> 9) & 3, hd = q >> 11;     // fr = kt*2+nt
      const int kt = fr >> 1, nt = fr & 1;
      const int s = kt * 32 + (lane >> 4) * 8 + jj;  // slot index
      const int forig = (s & 3) * 16 + (s >> 2);     // slot -> original f
      const int o = nt * 16 + (lane & 15);
      hw1b[q] = S[(hd * 64 + forig) * 36 + o];
    }
    return;
  }

  // ---- bid 147: hb1e[n][o] = hb1[n][o] + sum_s hw1[n][s][o]*db[s] (exact)
  if (tid < 128) {
    const int n = tid >> 5, o = tid & 31;
    float acc = hb1[n * 32 + o];
#pragma unroll
    for (int s = 0; s < 64; ++s)
      acc += hw1[n * 2048 + s * 32 + o] * db[s];
    hb1e[tid] = acc;
  }
}

// ---------------------------------------------------------------------------
// K23: fused DISCO conv + head MLP + final MLP. grid (8,128,2), block 256.
// (byte-identical to R6 -- isolates the k01 change)
// ---------------------------------------------------------------------------
__global__ __launch_bounds__(256, 3) void k23_fused(
    const float* __restrict__ x,    const short* __restrict__ wcb,
    const short* __restrict__ hw1b, const float* __restrict__ hb1e,
    const float* __restrict__ hw2,  const float* __restrict__ hb2,
    const short* __restrict__ fw1s, const short* __restrict__ fw2s,
    const short* __restrict__ fw3s,
    const float* __restrict__ fb1,  const float* __restrict__ fb2,
    const float* __restrict__ fb3,  float* __restrict__ outb) {
  // layout: phase A: sX [0,24832), sD [24832,43264), sM [50176,52352)
  //         phase B: sT1 [0,33280), sT2 [33280,50176), sM persists
  __shared__ __align__(16) char smem[52352];
  short* sX  = (short*)smem;
  short* sM  = (short*)(smem + 50176);

  const int tid = threadIdx.x;
  const int w0  = blockIdx.x * 32;
  const int h   = blockIdx.y;
  const int b   = blockIdx.z;

  {  // zero-fill sX (pads must be 0.0bf16, never garbage)
    int4* p = (int4*)sX;
    int4 z; z.x = z.y = z.z = z.w = 0;
    for (int e = tid; e < (32 * 388) / 8; e += 256) p[e] = z;
  }
  __syncthreads();

  // stage x tile as bf16; r-outer => wp = e>>4 (no integer division)
#pragma unroll 1
  for (int r = 0; r < 7; ++r) {
    int hr = h - 3 + r; hr = hr < 0 ? 0 : (hr > 127 ? 127 : hr);
    const float* __restrict__ xrow = x + (size_t)((b * 128 + hr) * 256) * 34;
    short* __restrict__ sxr = sX + r * 48;
    for (int e = tid; e < 39 * 16; e += 256) {
      const int c2 = e & 15;
      const int wp = e >> 4;
      const int wr = (w0 - 3 + wp) & 255;
      const float2 v = *(const float2*)&xrow[wr * 34 + c2 * 2];
      short* dp = sxr + (c2 * 2) * 388 + wp;
      dp[0]   = f2bf_fast(v.x);
      dp[388] = f2bf_fast(v.y);
    }
  }

  // sincos passthrough (independent of everything below)
  if (tid < 64) {
    const int wl = tid >> 1;
    const int sc = tid & 1;
    const int idx = ((b * 128 + h) * 256 + (w0 + wl)) * 34 + 32 + sc;
    outb[idx] = x[idx];
  }
  __syncthreads();

  const int lane = tid & 63, lm = lane & 15, lq = lane >> 4;
  const int n = tid >> 6;  // wave == head in phase A
  const int rowbase = ((b * 128 + h) * 256) * 34;

  float hb1v[2], hw2v[2];
#pragma unroll
  for (int nt = 0; nt < 2; ++nt) {
    hb1v[nt] = hb1e[n * 32 + nt * 16 + lm];
    hw2v[nt] = hw2[n * 32 + nt * 16 + lm];
  }
  const float hb2n = hb2[n];

  // conv B-frags: [par][kt][nt] (block-uniform per h)
  bfrag cB[2][2][4];
#pragma unroll
  for (int par = 0; par < 2; ++par)
#pragma unroll
    for (int kt = 0; kt < 2; ++kt)
#pragma unroll
      for (int nt = 0; nt < 4; ++nt)
        cB[par][kt][nt] = *(const bfrag*)(wcb + h * 8192 +
                            ((par * 2 + kt) * 4 + nt) * 512 + lane * 8);
  // MLP1 B-frags (slot-K): [kt][nt]
  bfrag mB[2][2];
#pragma unroll
  for (int kt = 0; kt < 2; ++kt)
#pragma unroll
    for (int nt = 0; nt < 2; ++nt)
      mB[kt][nt] = *(const bfrag*)(hw1b + n * 2048 + (kt * 2 + nt) * 512 + lane * 8);

  short* sDw = (short*)(smem + 24832) + n * (2 * 1152);
  const int* tpB = (const int*)sX;

  auto ldtaps = [&](int c, bfi4& u0, bfi4& u1) {
    const int base0 = c * 194 + lq * 24 + lm;
    u0.i.x = tpB[base0];      u0.i.y = tpB[base0 + 1];
    u0.i.z = tpB[base0 + 2];  u0.i.w = tpB[base0 + 3];
    u1.i.x = tpB[base0 + 96]; u1.i.y = tpB[base0 + 97];
    u1.i.z = tpB[base0 + 98]; u1.i.w = tpB[base0 + 99];
  };
  auto convf = [&](const bfi4& u0, const bfi4& u1, int par, ffrag* d) {
#pragma unroll
    for (int nt = 0; nt < 4; ++nt) d[nt] = ffrag{0.f, 0.f, 0.f, 0.f};
#pragma unroll
    for (int nt = 0; nt < 4; ++nt) {
      d[nt] = __builtin_amdgcn_mfma_f32_16x16x32_bf16(u0.b, cB[par][0][nt], d[nt], 0, 0, 0);
      d[nt] = __builtin_amdgcn_mfma_f32_16x16x32_bf16(u1.b, cB[par][1][nt], d[nt], 0, 0, 0);
    }
  };
  auto writeD = [&](const ffrag* d, short* buf) {
#pragma unroll
    for (int rr = 0; rr < 4; ++rr) {
      int2 w;
      w.x = pkbf(d[0][rr], d[1][rr]);
      w.y = pkbf(d[2][rr], d[3][rr]);
      *(int2*)(buf + (lq * 4 + rr) * 72 + lm * 4) = w;
    }
  };
  auto mlpStage = [&](const short* buf, int i, int par) {
    bfrag a10 = *(const bfrag*)(buf + lm * 72 + lq * 8);
    bfrag a11 = *(const bfrag*)(buf + lm * 72 + 32 + lq * 8);
    ffrag h10 = {0.f, 0.f, 0.f, 0.f}, h11 = {0.f, 0.f, 0.f, 0.f};
    h10 = __builtin_amdgcn_mfma_f32_16x16x32_bf16(a10, mB[0][0], h10, 0, 0, 0);
    h10 = __builtin_amdgcn_mfma_f32_16x16x32_bf16(a11, mB[1][0], h10, 0, 0, 0);
    h11 = __builtin_amdgcn_mfma_f32_16x16x32_bf16(a10, mB[0][1], h11, 0, 0, 0);
    h11 = __builtin_amdgcn_mfma_f32_16x16x32_bf16(a11, mB[1][1], h11, 0, 0, 0);
    const int c = n * 8 + i;
#pragma unroll
    for (int rr = 0; rr < 4; ++rr) {
      float v = gelu_f(h10[rr] + hb1v[0]) * hw2v[0] +
                gelu_f(h11[rr] + hb1v[1]) * hw2v[1];
      v = reduce16(v);
      if (lm == 0) {
        const int p = 2 * (lq * 4 + rr) + par;
        const float res = x[rowbase + (w0 + p) * 34 + c];  // exact fp32 x
        sM[p * 34 + c] = f2bf_fast(v + hb2n + res);
      }
    }
  };

  // ---- phase A main loop: software-pipelined, double-buffered sD
  bfi4 u0, u1;
  ldtaps(n * 8, u0, u1);
  ffrag dA[4], dB[4];
  convf(u0, u1, 0, dA);
#pragma unroll 1
  for (int i = 0; i < 8; ++i) {
    short* b0 = sDw;
    short* b1 = sDw + 1152;
    writeD(dA, b0);
    convf(u0, u1, 1, dB);           // overlaps mlpStage(b0) chain
    mlpStage(b0, i, 0);
    writeD(dB, b1);
    if (i < 7) {
      ldtaps(n * 8 + i + 1, u0, u1);
      convf(u0, u1, 0, dA);         // overlaps mlpStage(b1) chain
    }
    mlpStage(b1, i, 1);
  }
  __syncthreads();

  // ---- phase B: fused MLP 32->512(gelu)->256(gelu)->32 (+residual)
  short* sT1 = (short*)smem;
  short* sT2 = (short*)(smem + 33280);
  const int wave = n;
  const int koff = lq * 8;
  const int mt3 = wave & 1;
  const int nt3 = wave >> 1;
  const int col3 = nt3 * 16 + lm;
  const int pixg = (b * 128 + h) * 256 + w0;

  // hoisted loads
  bfrag aF[2];
#pragma unroll
  for (int mt = 0; mt < 2; ++mt)
    aF[mt] = *(const bfrag*)(sM + (mt * 16 + lm) * 34 + koff);
  bfrag b1f[8];
#pragma unroll
  for (int ni = 0; ni < 8; ++ni)
    b1f[ni] = *(const bfrag*)(fw1s + (wave * 8 + ni) * 512 + lane * 8);
  bfrag w3f[8];
#pragma unroll
  for (int kt = 0; kt < 8; ++kt)
    w3f[kt] = *(const bfrag*)(fw3s + nt3 * 512 + kt * 1024 + lane * 8);
  float res3[4];
#pragma unroll
  for (int r = 0; r < 4; ++r)
    res3[r] = bf2f(sM[(mt3 * 16 + lq * 4 + r) * 34 + col3]);

  // layer 1
#pragma unroll
  for (int ni = 0; ni < 8; ++ni) {
    const int nt = wave * 8 + ni;
#pragma unroll
    for (int mt = 0; mt < 2; ++mt) {
      ffrag c = {0.f, 0.f, 0.f, 0.f};
      c = __builtin_amdgcn_mfma_f32_16x16x32_bf16(aF[mt], b1f[ni], c, 0, 0, 0);
      const int col = nt * 16 + lm;
      const float bias = fb1[col];
#pragma unroll
      for (int r = 0; r < 4; ++r) {
        const int row = mt * 16 + lq * 4 + r;
        sT1[row * 520 + col] = f2bf_fast(gelu_f(c[r] + bias));
      }
    }
  }
  __syncthreads();

  // layer 2 with distance-1 B prefetch
  const int n0 = wave * 4;
  ffrag acc[2][4];
#pragma unroll
  for (int mt = 0; mt < 2; ++mt)
#pragma unroll
    for (int ni = 0; ni < 4; ++ni) acc[mt][ni] = ffrag{0.f, 0.f, 0.f, 0.f};

  const short* sA0 = &sT1[lm * 520 + koff];
  const short* sA1 = sA0 + 16 * 520;
  const short* w2p = fw2s + n0 * 512 + lane * 8;

  bfrag bv[4];
#pragma unroll
  for (int ni = 0; ni < 4; ++ni)
    bv[ni] = *(const bfrag*)(w2p + ni * 512);

#pragma unroll 2
  for (int kt = 0; kt < 16; ++kt) {
    bfrag bnext[4];
    if (kt < 15) {
#pragma unroll
      for (int ni = 0; ni < 4; ++ni)
        bnext[ni] = *(const bfrag*)(w2p + (kt + 1) * 8192 + ni * 512);
    }
    const bfrag a0 = *(const bfrag*)(sA0 + kt * 32);
    const bfrag a1 = *(const bfrag*)(sA1 + kt * 32);
#pragma unroll
    for (int ni = 0; ni < 4; ++ni) {
      acc[0][ni] = __builtin_amdgcn_mfma_f32_16x16x32_bf16(a0, bv[ni], acc[0][ni], 0, 0, 0);
      acc[1][ni] = __builtin_amdgcn_mfma_f32_16x16x32_bf16(a1, bv[ni], acc[1][ni], 0, 0, 0);
    }
    if (kt < 15) {
#pragma unroll
      for (int ni = 0; ni < 4; ++ni) bv[ni] = bnext[ni];
    }
  }
#pragma unroll
  for (int mt = 0; mt < 2; ++mt)
#pragma unroll
    for (int ni = 0; ni < 4; ++ni) {
      const int col = (n0 + ni) * 16 + lm;
      const float bias = fb2[col];
#pragma unroll
      for (int r = 0; r < 4; ++r) {
        const int row = mt * 16 + lq * 4 + r;
        sT2[row * 264 + col] = f2bf_fast(gelu_f(acc[mt][ni][r] + bias));
      }
    }
  __syncthreads();

  // layer 3
  ffrag c3 = {0.f, 0.f, 0.f, 0.f};
  const short* sA3 = &sT2[(mt3 * 16 + lm) * 264 + koff];
#pragma unroll
  for (int kt = 0; kt < 8; ++kt) {
    const bfrag a = *(const bfrag*)(sA3 + kt * 32);
    c3 = __builtin_amdgcn_mfma_f32_16x16x32_bf16(a, w3f[kt], c3, 0, 0, 0);
  }
  {
    const float bias = fb3[col3];
#pragma unroll
    for (int r = 0; r < 4; ++r) {
      const int row = mt3 * 16 + lq * 4 + r;
      outb[(pixg + row) * 34 + col3] = c3[r] + bias + res3[r];
    }
  }
}

// ---------------------------------------------------------------------------
extern "C" void kernel_launch(void* const* d_in, const int* in_sizes, int n_in,
                              void* d_out, int out_size, void* d_ws, size_t ws_size,
                              hipStream_t stream) {
  const float* x   = (const float*)d_in[0];
  const float* psi = (const float*)d_in[1];
  const float* dw  = (const float*)d_in[2];
  const float* db  = (const float*)d_in[3];
  const float* hw1 = (const float*)d_in[4];
  const float* hb1 = (const float*)d_in[5];
  const float* hw2 = (const float*)d_in[6];
  const float* hb2 = (const float*)d_in[7];
  const float* fw1 = (const float*)d_in[8];
  const float* fb1 = (const float*)d_in[9];
  const float* fw2 = (const float*)d_in[10];
  const float* fb2 = (const float*)d_in[11];
  const float* fw3 = (const float*)d_in[12];
  const float* fb3 = (const float*)d_in[13];
  float* outb = (float*)d_out;

  // workspace
  short* wcb  = (short*)d_ws;        // 128*8192 = 1048576 shorts
  short* fw1s = wcb + 1048576;       // 16384
  short* fw2s = fw1s + 16384;        // 131072
  short* fw3s = fw2s + 131072;       // 8192
  short* hw1b = fw3s + 8192;         // 8192
  float* hb1e = (float*)(hw1b + 8192);  // 128 floats

  hipLaunchKernelGGL(k01_prep, dim3(148), dim3(256), 0, stream,
                     psi, dw, db, fw1, fw2, fw3, hw1, hb1,
                     wcb, fw1s, fw2s, fw3s, hw1b, hb1e);
  hipLaunchKernelGGL(k23_fused, dim3(8, 128, 2), dim3(256), 0, stream,
                     x, wcb, hw1b, hb1e, hw2, hb2,
                     fw1s, fw2s, fw3s, fb1, fb2, fb3, outb);
}

// Round 9
// 170.299 us; speedup vs baseline: 1.1687x; 1.1687x over previous
//
#include <hip/hip_runtime.h>
#include <math.h>

// Problem constants
// B=2, H=128, W=256, MD=34, LD=32, NH=4, HD=8, SH=64, K=25, P=7, R=3,
// FF1=512, FF2=256

typedef __attribute__((ext_vector_type(8))) short bfrag;    // 8 bf16 = 4 VGPR
typedef __attribute__((ext_vector_type(4))) float ffrag;    // 4 f32 acc
typedef __attribute__((ext_vector_type(4))) short short4v;  // 8B

union bfi4 { int4 i; bfrag b; };

// Fast tanh-form GELU (~7 VALU ops, |err| vs erf-GELU ~3e-3)
__device__ __forceinline__ float gelu_f(float v) {
  const float z = v * (2.3022077484f + 0.1029451564f * v * v);  // log2e folded
  const float e = __builtin_amdgcn_exp2f(-z);
  return v * __builtin_amdgcn_rcpf(1.0f + e);
}

// exact RNE (cold paths: weight prep)
__device__ __forceinline__ short f2bf(float f) {
  union { float f; unsigned u; } v; v.f = f;
  unsigned r = (v.u + 0x7fffu + ((v.u >> 16) & 1u)) >> 16;
  return (short)r;
}

// round-half-up (2 VALU ops)
__device__ __forceinline__ short f2bf_fast(float f) {
  union { float f; unsigned u; } v; v.f = f;
  return (short)((v.u + 0x8000u) >> 16);
}

__device__ __forceinline__ float bf2f(short s) {
  union { float f; unsigned u; } v;
  v.u = ((unsigned)(unsigned short)s) << 16;
  return v.f;
}

// pack two f32 -> bf16 pair in one dword: (bf(b)<<16)|bf(a); 3 VALU ops
__device__ __forceinline__ int pkbf(float a, float b) {
  union { float f; unsigned u; } va, vb; va.f = a; vb.f = b;
  return (int)__builtin_amdgcn_perm(vb.u + 0x8000u, va.u + 0x8000u, 0x07060302u);
}

// DPP cross-lane add; butterfly reduction over 16 lanes (all lanes get sum).
template <int CTRL>
__device__ __forceinline__ float dpp_add(float v) {
  union { float f; int i; } s, t;
  s.f = v;
  t.i = __builtin_amdgcn_update_dpp(0, s.i, CTRL, 0xf, 0xf, true);
  return v + t.f;
}
__device__ __forceinline__ float reduce16(float v) {
  v = dpp_add<0xB1>(v);    // quad_perm [1,0,3,2]  = xor1
  v = dpp_add<0x4E>(v);    // quad_perm [2,3,0,1]  = xor2
  v = dpp_add<0x141>(v);   // row_half_mirror      ~ xor4 after fold
  v = dpp_add<0x140>(v);   // row_mirror           ~ xor8 after fold
  return v;
}

// staged bf16 short4 store helper
__device__ __forceinline__ void st4bf(short* p, float4 v) {
  short4v s;
  s[0] = f2bf(v.x); s[1] = f2bf(v.y); s[2] = f2bf(v.z); s[3] = f2bf(v.w);
  *(short4v*)p = s;
}

// ---------------------------------------------------------------------------
// K01: weight prep.
// bid 0..127 : wcb[h]. NEW: lane=f holds dw in 25 VGPRs; psi read via
//   wave-uniform scalar loads; 49-col dot split across 4 waves; fragment
//   emission reads the [f][49] bf16 tile (kills ~6400 gathered ds_reads).
// bid 128..143: fw2 kt-tile transposes. 144: fw1. 145: fw3. 146: hw1.
// bid 147: hb1e (db fold).
// ---------------------------------------------------------------------------
__global__ __launch_bounds__(256) void k01_prep(
    const float* __restrict__ psi, const float* __restrict__ dw,
    const float* __restrict__ db,
    const float* __restrict__ fw1, const float* __restrict__ fw2,
    const float* __restrict__ fw3, const float* __restrict__ hw1,
    const float* __restrict__ hb1,
    short* __restrict__ wcb, short* __restrict__ fw1s,
    short* __restrict__ fw2s, short* __restrict__ fw3s,
    short* __restrict__ hw1b, float* __restrict__ hb1e) {
  __shared__ __align__(16) char sm[33280];
  const int bid = blockIdx.x;
  const int tid = threadIdx.x;

  if (bid < 128) {            // ---- wcb: conv weight fragments per latitude
    short* tile = (short*)sm;            // [f 64][p pad 52]
    const int h = bid;
    const int lane = tid & 63;
    const int w = __builtin_amdgcn_readfirstlane(tid >> 6);
    float dwreg[25];
#pragma unroll
    for (int kk = 0; kk < 25; ++kk) dwreg[kk] = dw[lane * 25 + kk];
    const int p0 = w * 13;
    const int pend = (p0 + 13 < 49) ? (p0 + 13) : 49;
#pragma unroll 1
    for (int p = p0; p < pend; ++p) {
      float acc = 0.f;
#pragma unroll
      for (int kk = 0; kk < 25; ++kk)
        acc += dwreg[kk] * psi[kk * 6272 + h * 49 + p];   // uniform -> s_load
      tile[lane * 52 + p] = f2bf(acc);
    }
    __syncthreads();
    short* outp = wcb + h * 8192;
    for (int idx = tid; idx < 8192; idx += 256) {
      const int jj = idx & 7, ln = (idx >> 3) & 63;
      const int nt = (idx >> 9) & 3, kt = (idx >> 11) & 1, par = idx >> 12;
      const int k = kt * 32 + (ln >> 4) * 8 + jj;
      const int f = nt * 16 + (ln & 15);
      const int r = k >> 3, dlt = k & 7;
      const int j = par ? (dlt - 1) : dlt;
      short v = 0;
      if (r < 7 && j >= 0 && j < 7) v = tile[f * 52 + r * 7 + j];
      outp[idx] = v;
    }
    return;
  }

  if (bid < 144) {            // ---- fw2 kt-tile transpose: K rows 32, N 256
    short* S = (short*)sm;               // [32][260]
    const int kt = bid - 128;
    const float* src = fw2 + kt * 8192;
    for (int q = tid; q < 2048; q += 256) {
      const int lin = q * 4;
      const int kk = lin >> 8, nn = lin & 255;
      st4bf(S + kk * 260 + nn, *(const float4*)(src + lin));
    }
    __syncthreads();
    short* dst = fw2s + kt * 8192;
    for (int q = tid; q < 8192; q += 256) {
      const int jj = q & 7, lane = (q >> 3) & 63, nt = q >> 9;
      const int kk = (lane >> 4) * 8 + jj, nn = nt * 16 + (lane & 15);
      dst[q] = S[kk * 260 + nn];
    }
    return;
  }

  if (bid == 144) {           // ---- fw1 transpose: K 32, N 512
    short* S = (short*)sm;               // [32][516]
    for (int q = tid; q < 4096; q += 256) {
      const int lin = q * 4;
      const int kk = lin >> 9, nn = lin & 511;
      st4bf(S + kk * 516 + nn, *(const float4*)(fw1 + lin));
    }
    __syncthreads();
    for (int q = tid; q < 16384; q += 256) {
      const int jj = q & 7, lane = (q >> 3) & 63, nt = q >> 9;
      const int kk = (lane >> 4) * 8 + jj, nn = nt * 16 + (lane & 15);
      fw1s[q] = S[kk * 516 + nn];
    }
    return;
  }

  if (bid == 145) {           // ---- fw3 transpose: K 256, N 32
    short* S = (short*)sm;               // [256][36]
    for (int q = tid; q < 2048; q += 256) {
      const int lin = q * 4;
      const int kk = lin >> 5, nn = lin & 31;
      st4bf(S + kk * 36 + nn, *(const float4*)(fw3 + lin));
    }
    __syncthreads();
    for (int q = tid; q < 8192; q += 256) {
      const int jj = q & 7, lane = (q >> 3) & 63;
      const int nt = (q >> 9) & 1, kt = q >> 10;
      const int kk = kt * 32 + (lane >> 4) * 8 + jj, nn = nt * 16 + (lane & 15);
      fw3s[q] = S[kk * 36 + nn];
    }
    return;
  }

  if (bid == 146) {           // ---- hw1 transpose (slot-K): rows (n,s), N 32
    short* S = (short*)sm;               // [256][36]
    for (int q = tid; q < 2048; q += 256) {
      const int lin = q * 4;
      const int row = lin >> 5, nn = lin & 31;
      st4bf(S + row * 36 + nn, *(const float4*)(hw1 + lin));
    }
    __syncthreads();
    for (int q = tid; q < 8192; q += 256) {
      const int jj = q & 7, lane = (q >> 3) & 63;
      const int fr = (q >> 9) & 3, hd = q >> 11;     // fr = kt*2+nt
      const int kt = fr >> 1, nt = fr & 1;
      const int s = kt * 32 + (lane >> 4) * 8 + jj;  // slot index
      const int forig = (s & 3) * 16 + (s >> 2);     // slot -> original f
      const int o = nt * 16 + (lane & 15);
      hw1b[q] = S[(hd * 64 + forig) * 36 + o];
    }
    return;
  }

  // ---- bid 147: hb1e[n][o] = hb1[n][o] + sum_s hw1[n][s][o]*db[s] (exact)
  if (tid < 128) {
    const int n = tid >> 5, o = tid & 31;
    float acc = hb1[n * 32 + o];
#pragma unroll
    for (int s = 0; s < 64; ++s)
      acc += hw1[n * 2048 + s * 32 + o] * db[s];
    hb1e[tid] = acc;
  }
}

// ---------------------------------------------------------------------------
// K23: fused DISCO conv + head MLP + final MLP. grid (8,128,2), block 256.
// LDS diet -> 4 blocks/CU (36224 B):
//   phase A: sX [0,24832) + single-buffer sD [24832,34048) + sM [34048,36224)
//   phase B: sT1h [0,16896) + sT2 [16896,33792) + sM persists
// Phase B runs split-K: t1 produced in two 256-col halves, layer2 partial
// accumulation per half (barriers between). Residuals come from sX/sM (LDS).
// ---------------------------------------------------------------------------
__global__ __launch_bounds__(256, 4) void k23_fused(
    const float* __restrict__ x,    const short* __restrict__ wcb,
    const short* __restrict__ hw1b, const float* __restrict__ hb1e,
    const float* __restrict__ hw2,  const float* __restrict__ hb2,
    const short* __restrict__ fw1s, const short* __restrict__ fw2s,
    const short* __restrict__ fw3s,
    const float* __restrict__ fb1,  const float* __restrict__ fb2,
    const float* __restrict__ fb3,  float* __restrict__ outb) {
  __shared__ __align__(16) char smem[36224];
  short* sX = (short*)smem;
  short* sM = (short*)(smem + 34048);

  const int tid = threadIdx.x;
  const int w0  = blockIdx.x * 32;
  const int h   = blockIdx.y;
  const int b   = blockIdx.z;

  {  // zero-fill sX (pads must be 0.0bf16, never garbage)
    int4* p = (int4*)sX;
    int4 z; z.x = z.y = z.z = z.w = 0;
    for (int e = tid; e < (32 * 388) / 8; e += 256) p[e] = z;
  }
  __syncthreads();

  // stage x tile as bf16; r-outer => wp = e>>4 (no integer division)
#pragma unroll 1
  for (int r = 0; r < 7; ++r) {
    int hr = h - 3 + r; hr = hr < 0 ? 0 : (hr > 127 ? 127 : hr);
    const float* __restrict__ xrow = x + (size_t)((b * 128 + hr) * 256) * 34;
    short* __restrict__ sxr = sX + r * 48;
    for (int e = tid; e < 39 * 16; e += 256) {
      const int c2 = e & 15;
      const int wp = e >> 4;
      const int wr = (w0 - 3 + wp) & 255;
      const float2 v = *(const float2*)&xrow[wr * 34 + c2 * 2];
      short* dp = sxr + (c2 * 2) * 388 + wp;
      dp[0]   = f2bf_fast(v.x);
      dp[388] = f2bf_fast(v.y);
    }
  }

  // sincos passthrough (independent of everything below)
  if (tid < 64) {
    const int wl = tid >> 1;
    const int sc = tid & 1;
    const int idx = ((b * 128 + h) * 256 + (w0 + wl)) * 34 + 32 + sc;
    outb[idx] = x[idx];
  }
  __syncthreads();

  const int lane = tid & 63, lm = lane & 15, lq = lane >> 4;
  const int n = tid >> 6;  // wave == head in phase A

  float hb1v[2], hw2v[2];
#pragma unroll
  for (int nt = 0; nt < 2; ++nt) {
    hb1v[nt] = hb1e[n * 32 + nt * 16 + lm];
    hw2v[nt] = hw2[n * 32 + nt * 16 + lm];
  }
  const float hb2n = hb2[n];

  // conv B-frags: [par][kt][nt] (block-uniform per h)
  bfrag cB[2][2][4];
#pragma unroll
  for (int par = 0; par < 2; ++par)
#pragma unroll
    for (int kt = 0; kt < 2; ++kt)
#pragma unroll
      for (int nt = 0; nt < 4; ++nt)
        cB[par][kt][nt] = *(const bfrag*)(wcb + h * 8192 +
                            ((par * 2 + kt) * 4 + nt) * 512 + lane * 8);
  // MLP1 B-frags (slot-K): [kt][nt]
  bfrag mB[2][2];
#pragma unroll
  for (int kt = 0; kt < 2; ++kt)
#pragma unroll
    for (int nt = 0; nt < 2; ++nt)
      mB[kt][nt] = *(const bfrag*)(hw1b + n * 2048 + (kt * 2 + nt) * 512 + lane * 8);

  short* sDw = (short*)(smem + 24832) + n * 1152;
  const int* tpB = (const int*)sX;

  // ---- phase A main loop (single-buffer sD; occupancy provides overlap)
#pragma unroll 1
  for (int i = 0; i < 8; ++i) {
    const int c = n * 8 + i;

    // tap A-frags (shared by both parities): dword-aligned gathers
    const int base0 = c * 194 + lq * 24 + lm;
    bfi4 u0, u1;
    u0.i.x = tpB[base0];      u0.i.y = tpB[base0 + 1];
    u0.i.z = tpB[base0 + 2];  u0.i.w = tpB[base0 + 3];
    u1.i.x = tpB[base0 + 96]; u1.i.y = tpB[base0 + 97];
    u1.i.z = tpB[base0 + 98]; u1.i.w = tpB[base0 + 99];

#pragma unroll
    for (int par = 0; par < 2; ++par) {
      ffrag dacc[4];
#pragma unroll
      for (int nt = 0; nt < 4; ++nt) dacc[nt] = ffrag{0.f, 0.f, 0.f, 0.f};
#pragma unroll
      for (int nt = 0; nt < 4; ++nt) {
        dacc[nt] = __builtin_amdgcn_mfma_f32_16x16x32_bf16(u0.b, cB[par][0][nt], dacc[nt], 0, 0, 0);
        dacc[nt] = __builtin_amdgcn_mfma_f32_16x16x32_bf16(u1.b, cB[par][1][nt], dacc[nt], 0, 0, 0);
      }

      // d -> sD: row = conv m, slots lm*4+nt packed -> one b64/row
#pragma unroll
      for (int rr = 0; rr < 4; ++rr) {
        int2 w;
        w.x = pkbf(dacc[0][rr], dacc[1][rr]);
        w.y = pkbf(dacc[2][rr], dacc[3][rr]);
        *(int2*)(sDw + (lq * 4 + rr) * 72 + lm * 4) = w;
      }
      // same-wave DS ordering -> no barrier

      bfrag a10 = *(const bfrag*)(sDw + lm * 72 + lq * 8);
      bfrag a11 = *(const bfrag*)(sDw + lm * 72 + 32 + lq * 8);
      ffrag h10 = {0.f, 0.f, 0.f, 0.f}, h11 = {0.f, 0.f, 0.f, 0.f};
      h10 = __builtin_amdgcn_mfma_f32_16x16x32_bf16(a10, mB[0][0], h10, 0, 0, 0);
      h10 = __builtin_amdgcn_mfma_f32_16x16x32_bf16(a11, mB[1][0], h10, 0, 0, 0);
      h11 = __builtin_amdgcn_mfma_f32_16x16x32_bf16(a10, mB[0][1], h11, 0, 0, 0);
      h11 = __builtin_amdgcn_mfma_f32_16x16x32_bf16(a11, mB[1][1], h11, 0, 0, 0);

#pragma unroll
      for (int rr = 0; rr < 4; ++rr) {
        float v = gelu_f(h10[rr] + hb1v[0]) * hw2v[0] +
                  gelu_f(h11[rr] + hb1v[1]) * hw2v[1];
        v = reduce16(v);
        const int p = 2 * (lq * 4 + rr) + par;
        const float res = bf2f(sX[c * 388 + 144 + 3 + p]);  // x center tap
        if (lm == 0) sM[p * 34 + c] = f2bf_fast(v + hb2n + res);
      }
    }
  }
  __syncthreads();

  // ---- phase B: fused MLP 32->512(gelu)->256(gelu)->32 (+residual),
  // split-K: t1 in two 256-col halves.
  short* sT1h = (short*)smem;
  short* sT2  = (short*)(smem + 16896);
  const int wave = n;
  const int koff = lq * 8;
  const int mt3 = wave & 1;
  const int nt3 = wave >> 1;
  const int col3 = nt3 * 16 + lm;
  const int pixg = (b * 128 + h) * 256 + w0;

  bfrag aF[2];
#pragma unroll
  for (int mt = 0; mt < 2; ++mt)
    aF[mt] = *(const bfrag*)(sM + (mt * 16 + lm) * 34 + koff);
  float res3[4];
#pragma unroll
  for (int r = 0; r < 4; ++r)
    res3[r] = bf2f(sM[(mt3 * 16 + lq * 4 + r) * 34 + col3]);

  const int n0 = wave * 4;
  ffrag acc[2][4];
#pragma unroll
  for (int mt = 0; mt < 2; ++mt)
#pragma unroll
    for (int ni = 0; ni < 4; ++ni) acc[mt][ni] = ffrag{0.f, 0.f, 0.f, 0.f};
  const short* w2base = fw2s + n0 * 512 + lane * 8;

#pragma unroll 1
  for (int H = 0; H < 2; ++H) {
    // layer 1, half H: waves produce cols [H*256, H*256+256)
    bfrag b1f[4];
#pragma unroll
    for (int ni = 0; ni < 4; ++ni)
      b1f[ni] = *(const bfrag*)(fw1s + (H * 16 + wave * 4 + ni) * 512 + lane * 8);
#pragma unroll
    for (int ni = 0; ni < 4; ++ni) {
      const int ntl = wave * 4 + ni;          // within-half tile
#pragma unroll
      for (int mt = 0; mt < 2; ++mt) {
        ffrag cc = {0.f, 0.f, 0.f, 0.f};
        cc = __builtin_amdgcn_mfma_f32_16x16x32_bf16(aF[mt], b1f[ni], cc, 0, 0, 0);
        const int colg = H * 256 + ntl * 16 + lm;
        const float bias = fb1[colg];
#pragma unroll
        for (int r = 0; r < 4; ++r) {
          const int row = mt * 16 + lq * 4 + r;
          sT1h[row * 264 + ntl * 16 + lm] = f2bf_fast(gelu_f(cc[r] + bias));
        }
      }
    }
    __syncthreads();

    // layer 2 partial accumulation over this half's K=256
#pragma unroll 2
    for (int kt = 0; kt < 8; ++kt) {
      bfrag bv[4];
#pragma unroll
      for (int ni = 0; ni < 4; ++ni)
        bv[ni] = *(const bfrag*)(w2base + (H * 8 + kt) * 8192 + ni * 512);
      const bfrag a0 = *(const bfrag*)(sT1h + lm * 264 + kt * 32 + koff);
      const bfrag a1 = *(const bfrag*)(sT1h + (16 + lm) * 264 + kt * 32 + koff);
#pragma unroll
      for (int ni = 0; ni < 4; ++ni) {
        acc[0][ni] = __builtin_amdgcn_mfma_f32_16x16x32_bf16(a0, bv[ni], acc[0][ni], 0, 0, 0);
        acc[1][ni] = __builtin_amdgcn_mfma_f32_16x16x32_bf16(a1, bv[ni], acc[1][ni], 0, 0, 0);
      }
    }
    __syncthreads();   // before next half overwrites sT1h
  }

  // t2 epilogue
#pragma unroll
  for (int mt = 0; mt < 2; ++mt)
#pragma unroll
    for (int ni = 0; ni < 4; ++ni) {
      const int col = (n0 + ni) * 16 + lm;
      const float bias = fb2[col];
#pragma unroll
      for (int r = 0; r < 4; ++r) {
        const int row = mt * 16 + lq * 4 + r;
        sT2[row * 264 + col] = f2bf_fast(gelu_f(acc[mt][ni][r] + bias));
      }
    }
  __syncthreads();

  // layer 3
  ffrag c3 = {0.f, 0.f, 0.f, 0.f};
  const short* sA3 = sT2 + (mt3 * 16 + lm) * 264 + koff;
#pragma unroll
  for (int kt = 0; kt < 8; ++kt) {
    const bfrag a = *(const bfrag*)(sA3 + kt * 32);
    const bfrag bw = *(const bfrag*)(fw3s + nt3 * 512 + kt * 1024 + lane * 8);
    c3 = __builtin_amdgcn_mfma_f32_16x16x32_bf16(a, bw, c3, 0, 0, 0);
  }
  {
    const float bias = fb3[col3];
#pragma unroll
    for (int r = 0; r < 4; ++r) {
      const int row = mt3 * 16 + lq * 4 + r;
      outb[(pixg + row) * 34 + col3] = c3[r] + bias + res3[r];
    }
  }
}

// ---------------------------------------------------------------------------
extern "C" void kernel_launch(void* const* d_in, const int* in_sizes, int n_in,
                              void* d_out, int out_size, void* d_ws, size_t ws_size,
                              hipStream_t stream) {
  const float* x   = (const float*)d_in[0];
  const float* psi = (const float*)d_in[1];
  const float* dw  = (const float*)d_in[2];
  const float* db  = (const float*)d_in[3];
  const float* hw1 = (const float*)d_in[4];
  const float* hb1 = (const float*)d_in[5];
  const float* hw2 = (const float*)d_in[6];
  const float* hb2 = (const float*)d_in[7];
  const float* fw1 = (const float*)d_in[8];
  const float* fb1 = (const float*)d_in[9];
  const float* fw2 = (const float*)d_in[10];
  const float* fb2 = (const float*)d_in[11];
  const float* fw3 = (const float*)d_in[12];
  const float* fb3 = (const float*)d_in[13];
  float* outb = (float*)d_out;

  // workspace
  short* wcb  = (short*)d_ws;        // 128*8192 = 1048576 shorts
  short* fw1s = wcb + 1048576;       // 16384
  short* fw2s = fw1s + 16384;        // 131072
  short* fw3s = fw2s + 131072;       // 8192
  short* hw1b = fw3s + 8192;         // 8192
  float* hb1e = (float*)(hw1b + 8192);  // 128 floats

  hipLaunchKernelGGL(k01_prep, dim3(148), dim3(256), 0, stream,
                     psi, dw, db, fw1, fw2, fw3, hw1, hb1,
                     wcb, fw1s, fw2s, fw3s, hw1b, hb1e);
  hipLaunchKernelGGL(k23_fused, dim3(8, 128, 2), dim3(256), 0, stream,
                     x, wcb, hw1b, hb1e, hw2, hb2,
                     fw1s, fw2s, fw3s, fb1, fb2, fb3, outb);
}